// Round 4
// baseline (281.573 us; speedup 1.0000x reference)
//
#include <hip/hip_runtime.h>
#include <hip/hip_bf16.h>

#define N_ 32
#define C_ 64
#define H_ 128
#define W_ 128
#define HW_ (H_ * W_)
#define CHW_ (C_ * HW_)

#define XT_STRIDE 72           // halfs per row (144 B, 16B-aligned); row = w+9, col = channel
#define XT_ROWS 146
#define CB_STRIDE 68           // floats per conv-buffer row (272 B, 16B-aligned)
#define SMEM_BYTES (XT_ROWS * XT_STRIDE * 2)   // 21024; convbuf 4*16*68*4 = 17408 fits inside

typedef __bf16 bf16x8 __attribute__((ext_vector_type(8)));
typedef float floatx4 __attribute__((ext_vector_type(4)));

__device__ inline unsigned short f2bf(float f) {
    __hip_bfloat16 h = __float2bfloat16(f);
    return *reinterpret_cast<unsigned short*>(&h);
}

// Pre-pack weights into MFMA A-fragment order (bf16).
// A[o][k], k = t*64 + i, from Wc[o*448 + i*7 + t].
__global__ void prepack_kernel(const float* __restrict__ Wc, uint4* __restrict__ Ap) {
    int idx = blockIdx.x * 256 + threadIdx.x;
    if (idx >= 14 * 4 * 64) return;
    int lane = idx & 63;
    int mt = (idx >> 6) & 3;
    int kt = idx >> 8;
    int m = mt * 16 + (lane & 15);
    int kbase = kt * 32 + (lane >> 4) * 8;
    unsigned int r[4];
    #pragma unroll
    for (int p = 0; p < 4; ++p) {
        unsigned int half[2];
        #pragma unroll
        for (int jj = 0; jj < 2; ++jj) {
            int k = kbase + 2 * p + jj;
            int t = k >> 6;
            int i = k & 63;
            half[jj] = f2bf(Wc[m * 448 + i * 7 + t]);
        }
        r[p] = half[0] | (half[1] << 16);
    }
    Ap[idx] = make_uint4(r[0], r[1], r[2], r[3]);
}

__global__ __launch_bounds__(256, 6) void fused_mfma_kernel(
    const float* __restrict__ x, const uint4* __restrict__ Ap,
    const float* __restrict__ p4w, float* __restrict__ out)
{
    // xT (bf16 staging, 21024 B) and convbuf (fp32, 17408 B) are never live
    // simultaneously: union them. LDS 21024 B -> 7 blocks/CU by LDS;
    // register budget (launch_bounds 256,6) -> 6 blocks/CU resident.
    __shared__ __attribute__((aligned(16))) char smem[SMEM_BYTES];
    unsigned short* xT = (unsigned short*)smem;
    float* convbuf = (float*)smem;

    // XCD-aware swizzle: xcd = b&7 (round-robin dispatch). Each XCD owns a
    // contiguous 16-row h-chunk per n, so epilogue tap rows (h-3,h-1,h+1)
    // hit the home XCD's L2 instead of re-fetching from HBM.
    const int b = blockIdx.x;
    const int xcd = b & 7;
    const int i_ = b >> 3;           // 0..511
    const int n = i_ >> 4;           // 0..31
    const int h = xcd * 16 + (i_ & 15);

    const int tid = threadIdx.x;
    const int wave = tid >> 6;
    const int lane = tid & 63;
    const int l16 = lane & 15;
    const int quad = lane >> 4;
    const float* xn = x + (size_t)n * CHW_;

    // Rolling weight-fragment stream (L2-resident after first blocks).
    // Frees the 56 VGPRs the resident afrag[14] used to pin.
    const uint4* ApW = Ap + wave * 64 + lane;
    uint4 bcur = ApW[0];

    // ---- zero pad rows (rows 0..8 and 137..145), dword writes ----
    // rows 0..8 = dwords [0,324); rows 137..145 = dwords [4932,5256)
    unsigned int* xz = (unsigned int*)xT;
    for (int i = tid; i < 648; i += 256) {
        int d = (i < 324) ? i : (4932 + (i - 324));
        xz[d] = 0u;
    }

    // ---- stage x row-h slice into xT (transposed, bf16) ----
    // Scalar coalesced loads: per pass, wave-uniform c0 (8 channels), w = lane
    // + const -> each of the 8 dword loads is one 256B fully-coalesced
    // transaction. Lane packs 8 consecutive c into ONE ds_write_b128 at
    // xT[(w+9)*72 + c0]. Write bank-group = (w+9 + c0/8) & 7; 64 consecutive
    // w -> 8 lanes/group -> conflict-free.
    const float* xrow = xn + h * W_;
    #pragma unroll
    for (int p = 0; p < 4; ++p) {
        const int c0 = wave * 8 + (p >> 1) * 32;       // 0,8,16,24,32,...,56
        const int w = (tid & 63) + (p & 1) * 64;       // 0..127
        const float* src = xrow + (size_t)c0 * HW_ + w;
        unsigned int pk[4];
        #pragma unroll
        for (int i = 0; i < 4; ++i) {
            float f0 = src[(size_t)(2 * i) * HW_];
            float f1 = src[(size_t)(2 * i + 1) * HW_];
            pk[i] = (unsigned int)f2bf(f0) | ((unsigned int)f2bf(f1) << 16);
        }
        *(uint4*)&xT[(w + 9) * XT_STRIDE + c0] = make_uint4(pk[0], pk[1], pk[2], pk[3]);
    }

    __syncthreads();

    // ---- MFMA K-loop: O[o0+16][128] for o0 = wave*16 ----
    // B-read bank-group = (l16 + quad + 3t) & 7: uniform 8 lanes/group ->
    // conflict-free ds_read_b128. Weight tile kt+1 prefetched while kt's
    // 8 MFMAs run.
    floatx4 acc[8];
    #pragma unroll
    for (int nt = 0; nt < 8; ++nt) acc[nt] = (floatx4){0.f, 0.f, 0.f, 0.f};

    const int base_half = l16 * XT_STRIDE + quad * 8;
    #pragma unroll
    for (int kt = 0; kt < 14; ++kt) {
        uint4 bnext = ApW[((kt < 13) ? (kt + 1) : 13) * 256];
        bf16x8 av = __builtin_bit_cast(bf16x8, bcur);
        int koff = (kt >> 1) * 3 * XT_STRIDE + (kt & 1) * 32;
        #pragma unroll
        for (int nt = 0; nt < 8; ++nt) {
            int off = base_half + koff + nt * 16 * XT_STRIDE;
            uint4 d = *(const uint4*)&xT[off];           // ds_read_b128, 16B-aligned
            bf16x8 bv = __builtin_bit_cast(bf16x8, d);
            acc[nt] = __builtin_amdgcn_mfma_f32_16x16x32_bf16(av, bv, acc[nt], 0, 0, 0);
        }
        bcur = bnext;
    }

    // xT is dead past here; convbuf aliases it — barrier before reuse.
    __syncthreads();

    // ---- epilogue in two w-halves (halves convbuf -> 21 KB LDS union) ----
    const float p0 = p4w[0], p1 = p4w[1], p2 = p4w[2];
    const int h1 = (h - 1 + H_) & 127;
    float* cw = convbuf + wave * 16 * CB_STRIDE;   // wave-private region

    #pragma unroll
    for (int hb = 0; hb < 2; ++hb) {
        // round-trip this half's conv result through LDS.
        // Write banks: (16*quad + 4*r + 16*nt + l16) % 32 -> 2-way (free).
        #pragma unroll
        for (int nt = 0; nt < 4; ++nt) {
            #pragma unroll
            for (int r = 0; r < 4; ++r)
                cw[(quad * 4 + r) * CB_STRIDE + nt * 16 + l16] = acc[hb * 4 + nt][r];
        }
        // t4 + fuse + coalesced float4 stores for w in [hb*64, hb*64+64).
        #pragma unroll
        for (int j2 = 0; j2 < 4; ++j2) {
            int o_ = j2 * 4 + quad;            // 0..15
            int w = hb * 64 + l16 * 4;
            int o = wave * 16 + o_;

            float4 cv = *(const float4*)&cw[o_ * CB_STRIDE + l16 * 4];

            const float* xc = xn + o * HW_;
            float4 xv = *(const float4*)(xc + h * W_ + w);

            int wsa = w + 2;                   // <= 126, no wrap
            int wsb = (w + 4) & 127;           // wraps only at w = 124
            float tap[3][4];
            #pragma unroll
            for (int k = 0; k < 3; ++k) {
                int hh = h1 + 2 * k - 2;
                if (hh >= 0 && hh < H_) {
                    const float* rowp = xc + hh * W_;
                    float2 a = *(const float2*)(rowp + wsa);
                    float2 b2 = *(const float2*)(rowp + wsb);
                    tap[k][0] = a.x; tap[k][1] = a.y; tap[k][2] = b2.x; tap[k][3] = b2.y;
                } else {
                    tap[k][0] = tap[k][1] = tap[k][2] = tap[k][3] = 0.f;
                }
            }
            float ov[4];
            float xa[4] = {xv.x, xv.y, xv.z, xv.w};
            float ca[4] = {cv.x, cv.y, cv.z, cv.w};
            #pragma unroll
            for (int e = 0; e < 4; ++e) {
                float t4 = p0 * tap[0][e] + p1 * tap[1][e] + p2 * tap[2][e];
                ov[e] = (xa[e] + ca[e]) * t4;
            }
            *(float4*)(out + (size_t)n * CHW_ + o * HW_ + h * W_ + w) =
                make_float4(ov[0], ov[1], ov[2], ov[3]);
        }
    }
}

extern "C" void kernel_launch(void* const* d_in, const int* in_sizes, int n_in,
                              void* d_out, int out_size, void* d_ws, size_t ws_size,
                              hipStream_t stream) {
    const float* x   = (const float*)d_in[0];
    const float* Wc  = (const float*)d_in[1];
    const float* p4w = (const float*)d_in[2];
    float* out       = (float*)d_out;
    uint4* Apack     = (uint4*)d_ws;   // 14*4*64*16 = 57344 B

    prepack_kernel<<<14, 256, 0, stream>>>(Wc, Apack);
    fused_mfma_kernel<<<N_ * H_, 256, 0, stream>>>(x, Apack, p4w, out);
}

// Round 6
// 273.500 us; speedup vs baseline: 1.0295x; 1.0295x over previous
//
#include <hip/hip_runtime.h>
#include <hip/hip_bf16.h>

#define N_ 32
#define C_ 64
#define H_ 128
#define W_ 128
#define HW_ (H_ * W_)
#define CHW_ (C_ * HW_)

#define XT_STRIDE 72           // halfs per row (144 B, 16B-aligned); row = w+9, col = channel
#define XT_ROWS 146
#define CB_STRIDE 130          // floats per conv-buffer row (full 64-row buffer)
#define SMEM_BYTES (64 * CB_STRIDE * 4)   // 33280 >= 146*72*2 = 21024 (union with xT)

typedef __bf16 bf16x8 __attribute__((ext_vector_type(8)));
typedef float floatx4 __attribute__((ext_vector_type(4)));

__device__ inline unsigned short f2bf(float f) {
    __hip_bfloat16 h = __float2bfloat16(f);
    return *reinterpret_cast<unsigned short*>(&h);
}

// Pre-pack weights into MFMA A-fragment order (bf16).
// A[o][k], k = t*64 + i, from Wc[o*448 + i*7 + t].
__global__ void prepack_kernel(const float* __restrict__ Wc, uint4* __restrict__ Ap) {
    int idx = blockIdx.x * 256 + threadIdx.x;
    if (idx >= 14 * 4 * 64) return;
    int lane = idx & 63;
    int mt = (idx >> 6) & 3;
    int kt = idx >> 8;
    int m = mt * 16 + (lane & 15);
    int kbase = kt * 32 + (lane >> 4) * 8;
    unsigned int r[4];
    #pragma unroll
    for (int p = 0; p < 4; ++p) {
        unsigned int half[2];
        #pragma unroll
        for (int jj = 0; jj < 2; ++jj) {
            int k = kbase + 2 * p + jj;
            int t = k >> 6;
            int i = k & 63;
            half[jj] = f2bf(Wc[m * 448 + i * 7 + t]);
        }
        r[p] = half[0] | (half[1] << 16);
    }
    Ap[idx] = make_uint4(r[0], r[1], r[2], r[3]);
}

__global__ __launch_bounds__(256) void fused_mfma_kernel(
    const float* __restrict__ x, const uint4* __restrict__ Ap,
    const float* __restrict__ p4w, float* __restrict__ out)
{
    // xT (bf16 staging, 21 KB) and convbuf (fp32, 33 KB) are never live
    // simultaneously: union them. LDS 33280 B -> 4 blocks/CU (same residency
    // as the 105us round-3 config -> preserves its L2 tap locality).
    __shared__ __attribute__((aligned(16))) char smem[SMEM_BYTES];
    unsigned short* xT = (unsigned short*)smem;
    float* convbuf = (float*)smem;

    // XCD-aware swizzle: xcd = b&7 (round-robin dispatch). Each XCD owns a
    // contiguous 16-row h-chunk per n, so epilogue tap rows (h-3,h-1,h+1)
    // hit the home XCD's L2 instead of re-fetching from HBM.
    const int b = blockIdx.x;
    const int xcd = b & 7;
    const int i_ = b >> 3;           // 0..511
    const int n = i_ >> 4;           // 0..31
    const int h = xcd * 16 + (i_ & 15);

    const int tid = threadIdx.x;
    const int wave = tid >> 6;
    const int lane = tid & 63;
    const int l16 = lane & 15;
    const int quad = lane >> 4;
    const float* xn = x + (size_t)n * CHW_;

    // Per-lane weight stream base: wave-INDEPENDENT now (every wave needs all
    // 4 o-tiles); rolling 1-deep prefetch, all L2 hits (Ap = 57 KB, pinned).
    const uint4* Apl = Ap + lane;

    // ---- zero pad rows (rows 0..8 and 137..145), dword writes ----
    // rows 0..8 = dwords [0,324); rows 137..145 = dwords [4932,5256)
    unsigned int* xz = (unsigned int*)xT;
    for (int i = tid; i < 648; i += 256) {
        int d = (i < 324) ? i : (4932 + (i - 324));
        xz[d] = 0u;
    }

    // ---- stage x row-h slice into xT (transposed, bf16) ----
    // Scalar coalesced loads: per pass, wave-uniform c0 (8 channels), w = lane
    // + const -> each of the 8 dword loads is one 256B fully-coalesced
    // transaction. Lane packs 8 consecutive c into ONE ds_write_b128 at
    // xT[(w+9)*72 + c0]. Write bank-group = (w+9 + c0/8) & 7; 64 consecutive
    // w -> 8 lanes/group -> conflict-free.
    const float* xrow = xn + h * W_;
    #pragma unroll
    for (int p = 0; p < 4; ++p) {
        const int c0 = wave * 8 + (p >> 1) * 32;       // 0,8,16,24,32,...,56
        const int w = (tid & 63) + (p & 1) * 64;       // 0..127
        const float* src = xrow + (size_t)c0 * HW_ + w;
        unsigned int pk[4];
        #pragma unroll
        for (int i = 0; i < 4; ++i) {
            float f0 = src[(size_t)(2 * i) * HW_];
            float f1 = src[(size_t)(2 * i + 1) * HW_];
            pk[i] = (unsigned int)f2bf(f0) | ((unsigned int)f2bf(f1) << 16);
        }
        *(uint4*)&xT[(w + 9) * XT_STRIDE + c0] = make_uint4(pk[0], pk[1], pk[2], pk[3]);
    }

    // preload kt=0 A-fragments for all 4 o-tiles while staging drains
    uint4 a0 = Apl[0 * 64];
    uint4 a1 = Apl[1 * 64];
    uint4 a2 = Apl[2 * 64];
    uint4 a3 = Apl[3 * 64];

    __syncthreads();

    // ---- MFMA K-loop, wave <-> w-range split ----
    // Wave owns nt in {2*wave, 2*wave+1} (w in [wave*32, wave*32+32)) and ALL
    // 4 o-tiles. Each xT B-fragment is read by exactly ONE wave: 2 ds_read_b128
    // per kt (vs 8 in the wave<->o split) -> block K-loop LDS reads 448 -> 112.
    // Weights roll through registers from L2: 4 loads/kt, 1-deep prefetch.
    // B-read bank-group = (l16 + 3t + 1 + quad + 4(kt&1)) & 7 (nt*16*72 = 0
    // mod 8 groups): exactly 8 lanes/group -> conflict-free.
    floatx4 acc[8];   // acc[ot*2 + j], j = nt - 2*wave
    #pragma unroll
    for (int i = 0; i < 8; ++i) acc[i] = (floatx4){0.f, 0.f, 0.f, 0.f};

    const int base_half = (wave * 2) * 16 * XT_STRIDE + l16 * XT_STRIDE + quad * 8;
    #pragma unroll
    for (int kt = 0; kt < 14; ++kt) {
        const int ktn = (kt < 13) ? (kt + 1) : 13;
        uint4 n0 = Apl[ktn * 256 + 0 * 64];
        uint4 n1 = Apl[ktn * 256 + 1 * 64];
        uint4 n2 = Apl[ktn * 256 + 2 * 64];
        uint4 n3 = Apl[ktn * 256 + 3 * 64];

        const int koff = (kt >> 1) * 3 * XT_STRIDE + (kt & 1) * 32;
        uint4 d0 = *(const uint4*)&xT[base_half + koff];                   // nt = 2*wave
        uint4 d1 = *(const uint4*)&xT[base_half + koff + 16 * XT_STRIDE];  // nt = 2*wave+1
        bf16x8 b0 = __builtin_bit_cast(bf16x8, d0);
        bf16x8 b1 = __builtin_bit_cast(bf16x8, d1);

        acc[0] = __builtin_amdgcn_mfma_f32_16x16x32_bf16(__builtin_bit_cast(bf16x8, a0), b0, acc[0], 0, 0, 0);
        acc[1] = __builtin_amdgcn_mfma_f32_16x16x32_bf16(__builtin_bit_cast(bf16x8, a0), b1, acc[1], 0, 0, 0);
        acc[2] = __builtin_amdgcn_mfma_f32_16x16x32_bf16(__builtin_bit_cast(bf16x8, a1), b0, acc[2], 0, 0, 0);
        acc[3] = __builtin_amdgcn_mfma_f32_16x16x32_bf16(__builtin_bit_cast(bf16x8, a1), b1, acc[3], 0, 0, 0);
        acc[4] = __builtin_amdgcn_mfma_f32_16x16x32_bf16(__builtin_bit_cast(bf16x8, a2), b0, acc[4], 0, 0, 0);
        acc[5] = __builtin_amdgcn_mfma_f32_16x16x32_bf16(__builtin_bit_cast(bf16x8, a2), b1, acc[5], 0, 0, 0);
        acc[6] = __builtin_amdgcn_mfma_f32_16x16x32_bf16(__builtin_bit_cast(bf16x8, a3), b0, acc[6], 0, 0, 0);
        acc[7] = __builtin_amdgcn_mfma_f32_16x16x32_bf16(__builtin_bit_cast(bf16x8, a3), b1, acc[7], 0, 0, 0);

        a0 = n0; a1 = n1; a2 = n2; a3 = n3;
    }

    // xT is dead past here; convbuf aliases it — barrier before reuse.
    __syncthreads();

    // ---- scatter conv result into convbuf (column-partitioned per wave) ----
    // D layout: m = ot*16 + quad*4 + r (o), n = l16 (+ wave*32 + j*16) (w).
    // Write banks: (520*quad + l16) % 32 = (8*quad + l16) % 32 -> 2-way (free).
    // Waves write disjoint column ranges; rows span all o -> needs the sync
    // below before the row-partitioned read-back.
    #pragma unroll
    for (int ot = 0; ot < 4; ++ot) {
        #pragma unroll
        for (int j = 0; j < 2; ++j) {
            #pragma unroll
            for (int r = 0; r < 4; ++r)
                convbuf[(ot * 16 + quad * 4 + r) * CB_STRIDE + wave * 32 + j * 16 + l16] =
                    acc[ot * 2 + j][r];
        }
    }

    __syncthreads();

    // ---- epilogue: t4 + fuse + coalesced float4 stores (round-3 verbatim) ----
    const float p0 = p4w[0], p1 = p4w[1], p2 = p4w[2];
    const int h1 = (h - 1 + H_) & 127;
    const float* cw = convbuf + wave * 16 * CB_STRIDE;   // this wave's o-rows

    #pragma unroll
    for (int j = 0; j < 8; ++j) {
        int idx = j * 64 + lane;           // 0..511
        int o_ = idx >> 5;                 // 0..15
        int w4 = idx & 31;
        int w = w4 * 4;
        int o = wave * 16 + o_;

        float4 cv = *(const float4*)&cw[o_ * CB_STRIDE + w];

        const float* xc = xn + o * HW_;
        float4 xv = *(const float4*)(xc + h * W_ + w);

        int wsrc = w + 2;
        float tap[3][4];
        #pragma unroll
        for (int k = 0; k < 3; ++k) {
            int hh = h1 + 2 * k - 2;
            if (hh >= 0 && hh < H_) {
                const float* rowp = xc + hh * W_;
                float2 a = *(const float2*)(rowp + wsrc);
                float2 b2 = *(const float2*)(rowp + ((wsrc + 2) & 127));
                tap[k][0] = a.x; tap[k][1] = a.y; tap[k][2] = b2.x; tap[k][3] = b2.y;
            } else {
                tap[k][0] = tap[k][1] = tap[k][2] = tap[k][3] = 0.f;
            }
        }
        float ov[4];
        float xa[4] = {xv.x, xv.y, xv.z, xv.w};
        float ca[4] = {cv.x, cv.y, cv.z, cv.w};
        #pragma unroll
        for (int e = 0; e < 4; ++e) {
            float t4 = p0 * tap[0][e] + p1 * tap[1][e] + p2 * tap[2][e];
            ov[e] = (xa[e] + ca[e]) * t4;
        }
        *(float4*)(out + (size_t)n * CHW_ + o * HW_ + h * W_ + w) =
            make_float4(ov[0], ov[1], ov[2], ov[3]);
    }
}

extern "C" void kernel_launch(void* const* d_in, const int* in_sizes, int n_in,
                              void* d_out, int out_size, void* d_ws, size_t ws_size,
                              hipStream_t stream) {
    const float* x   = (const float*)d_in[0];
    const float* Wc  = (const float*)d_in[1];
    const float* p4w = (const float*)d_in[2];
    float* out       = (float*)d_out;
    uint4* Apack     = (uint4*)d_ws;   // 14*4*64*16 = 57344 B

    prepack_kernel<<<14, 256, 0, stream>>>(Wc, Apack);
    fused_mfma_kernel<<<N_ * H_, 256, 0, stream>>>(x, Apack, p4w, out);
}

// Round 7
// 259.591 us; speedup vs baseline: 1.0847x; 1.0536x over previous
//
#include <hip/hip_runtime.h>
#include <hip/hip_bf16.h>

#define N_ 32
#define C_ 64
#define H_ 128
#define W_ 128
#define HW_ (H_ * W_)
#define CHW_ (C_ * HW_)

#define XT_STRIDE 72           // halfs per row (144 B, 16B-aligned); row = w+9, col = channel
#define XT_ROWS 146
#define CB_STRIDE 130          // floats per conv-buffer row (16 rows per wave)
#define SMEM_BYTES (4 * 16 * CB_STRIDE * 4)   // 33280 >= 146*72*2 = 21024

typedef __bf16 bf16x8 __attribute__((ext_vector_type(8)));
typedef float floatx4 __attribute__((ext_vector_type(4)));

__device__ inline unsigned short f2bf(float f) {
    __hip_bfloat16 h = __float2bfloat16(f);
    return *reinterpret_cast<unsigned short*>(&h);
}

// Pre-pack weights into MFMA A-fragment order (bf16).
// A[o][k], k = t*64 + i, from Wc[o*448 + i*7 + t].
__global__ void prepack_kernel(const float* __restrict__ Wc, uint4* __restrict__ Ap) {
    int idx = blockIdx.x * 256 + threadIdx.x;
    if (idx >= 14 * 4 * 64) return;
    int lane = idx & 63;
    int mt = (idx >> 6) & 3;
    int kt = idx >> 8;
    int m = mt * 16 + (lane & 15);
    int kbase = kt * 32 + (lane >> 4) * 8;
    unsigned int r[4];
    #pragma unroll
    for (int p = 0; p < 4; ++p) {
        unsigned int half[2];
        #pragma unroll
        for (int jj = 0; jj < 2; ++jj) {
            int k = kbase + 2 * p + jj;
            int t = k >> 6;
            int i = k & 63;
            half[jj] = f2bf(Wc[m * 448 + i * 7 + t]);
        }
        r[p] = half[0] | (half[1] << 16);
    }
    Ap[idx] = make_uint4(r[0], r[1], r[2], r[3]);
}

__global__ __launch_bounds__(256, 4) void fused_mfma_kernel(
    const float* __restrict__ x, const uint4* __restrict__ Ap,
    const float* __restrict__ p4w, float* __restrict__ out)
{
    // xT (bf16 staging, 21 KB) and convbuf (fp32, 33 KB) are never live
    // simultaneously: union them. LDS 33280 B -> 4 blocks/CU.
    // launch_bounds(256,4): 4 waves/EU target -> 128-VGPR budget, so the
    // compiler can batch-issue the staging/epilogue load groups below.
    __shared__ __attribute__((aligned(16))) char smem[SMEM_BYTES];
    unsigned short* xT = (unsigned short*)smem;
    float* convbuf = (float*)smem;

    // XCD-aware swizzle: xcd = b&7 (round-robin dispatch). Each XCD owns a
    // contiguous 16-row h-chunk per n, so epilogue tap rows (h-3,h-1,h+1)
    // hit the home XCD's L2 instead of re-fetching from HBM.
    const int b = blockIdx.x;
    const int xcd = b & 7;
    const int i_ = b >> 3;           // 0..511
    const int n = i_ >> 4;           // 0..31
    const int h = xcd * 16 + (i_ & 15);

    const int tid = threadIdx.x;
    const int wave = tid >> 6;
    const int lane = tid & 63;
    const int l16 = lane & 15;
    const int quad = lane >> 4;
    const float* xn = x + (size_t)n * CHW_;

    // ---- issue ALL 32 staging loads first (each one 256B coalesced) ----
    // One vmcnt wait before the pack instead of 4 serialized rounds.
    const float* xrow = xn + h * W_;
    float sv[4][8];
    #pragma unroll
    for (int p = 0; p < 4; ++p) {
        const int c0 = wave * 8 + (p >> 1) * 32;       // wave-uniform channel group
        const int w = lane + (p & 1) * 64;             // 0..127
        const float* src = xrow + (size_t)c0 * HW_ + w;
        #pragma unroll
        for (int i = 0; i < 8; ++i)
            sv[p][i] = src[(size_t)i * HW_];
    }

    // ---- afrag loads (needed only after the barrier; fill the shadow) ----
    uint4 afrag[14];
    #pragma unroll
    for (int kt = 0; kt < 14; ++kt)
        afrag[kt] = Ap[kt * 256 + wave * 64 + lane];

    // ---- zero pad rows (rows 0..8 and 137..145), dword writes ----
    unsigned int* xz = (unsigned int*)xT;
    for (int i = tid; i < 648; i += 256) {
        int d = (i < 324) ? i : (4932 + (i - 324));
        xz[d] = 0u;
    }

    // ---- pack + conflict-free ds_write_b128 ----
    // Write bank-group = (w+9 + c0/8) & 7; 64 consecutive w -> 8 lanes/group.
    #pragma unroll
    for (int p = 0; p < 4; ++p) {
        const int c0 = wave * 8 + (p >> 1) * 32;
        const int w = lane + (p & 1) * 64;
        unsigned int pk[4];
        #pragma unroll
        for (int i = 0; i < 4; ++i)
            pk[i] = (unsigned int)f2bf(sv[p][2 * i]) |
                    ((unsigned int)f2bf(sv[p][2 * i + 1]) << 16);
        *(uint4*)&xT[(w + 9) * XT_STRIDE + c0] = make_uint4(pk[0], pk[1], pk[2], pk[3]);
    }

    __syncthreads();

    // ---- MFMA K-loop: O[o0+16][128] for o0 = wave*16 (round-3 verbatim) ----
    // B-read bank-group = (row + chunk) & 7: 8 lanes/group -> conflict-free.
    floatx4 acc[8];
    #pragma unroll
    for (int nt = 0; nt < 8; ++nt) acc[nt] = (floatx4){0.f, 0.f, 0.f, 0.f};

    const int base_half = l16 * XT_STRIDE + quad * 8;
    #pragma unroll
    for (int kt = 0; kt < 14; ++kt) {
        bf16x8 av = __builtin_bit_cast(bf16x8, afrag[kt]);
        int koff = (kt >> 1) * 3 * XT_STRIDE + (kt & 1) * 32;
        #pragma unroll
        for (int nt = 0; nt < 8; ++nt) {
            int off = base_half + koff + nt * 16 * XT_STRIDE;
            uint4 d = *(const uint4*)&xT[off];           // ds_read_b128, 16B-aligned
            bf16x8 bv = __builtin_bit_cast(bf16x8, d);
            acc[nt] = __builtin_amdgcn_mfma_f32_16x16x32_bf16(av, bv, acc[nt], 0, 0, 0);
        }
    }

    // xT is dead past here; convbuf aliases it — barrier before reuse.
    __syncthreads();

    // ---- scatter conv result into convbuf (wave-private region) ----
    // Same-wave ds_write -> ds_read is ordered by lgkmcnt; no extra barrier.
    float* cw = convbuf + wave * 16 * CB_STRIDE;
    #pragma unroll
    for (int nt = 0; nt < 8; ++nt) {
        #pragma unroll
        for (int r = 0; r < 4; ++r)
            cw[(quad * 4 + r) * CB_STRIDE + nt * 16 + l16] = acc[nt][r];
    }

    // ---- epilogue pass 1: issue ALL tap/xv loads, reduce taps to t4 ----
    // ~56 independent loads pipeline against each other (vs 8 serial rounds).
    // Long-lived state: t4v (32) + xvv (32) floats; taps are transient fma fuel.
    const float p0 = p4w[0], p1 = p4w[1], p2 = p4w[2];
    const int h1 = (h - 1 + H_) & 127;
    const int hi = lane >> 5;           // 0..1
    const int w = (lane & 31) * 4;      // 0..124
    const int wsa = w + 2;              // <= 126, no wrap
    const int wsb = (w + 4) & 127;      // wraps only at w = 124

    float t4v[8][4];
    float4 xvv[8];
    #pragma unroll
    for (int j = 0; j < 8; ++j) {
        const int o_ = j * 2 + hi;               // 0..15
        const int o = wave * 16 + o_;
        const float* xc = xn + (size_t)o * HW_;
        xvv[j] = *(const float4*)(xc + h * W_ + w);
        float t4e[4] = {0.f, 0.f, 0.f, 0.f};
        #pragma unroll
        for (int k = 0; k < 3; ++k) {
            const int hh = h1 + 2 * k - 2;       // wave-uniform branch
            if (hh >= 0 && hh < H_) {
                const float pk_ = (k == 0) ? p0 : (k == 1) ? p1 : p2;
                const float* rowp = xc + hh * W_;
                float2 a = *(const float2*)(rowp + wsa);
                float2 b2 = *(const float2*)(rowp + wsb);
                t4e[0] += pk_ * a.x;  t4e[1] += pk_ * a.y;
                t4e[2] += pk_ * b2.x; t4e[3] += pk_ * b2.y;
            }
        }
        t4v[j][0] = t4e[0]; t4v[j][1] = t4e[1];
        t4v[j][2] = t4e[2]; t4v[j][3] = t4e[3];
    }

    // ---- epilogue pass 2: conv from LDS, fuse, coalesced float4 stores ----
    #pragma unroll
    for (int j = 0; j < 8; ++j) {
        const int o_ = j * 2 + hi;
        const int o = wave * 16 + o_;
        float4 cv = *(const float4*)&cw[o_ * CB_STRIDE + w];
        float ov[4];
        float xa[4] = {xvv[j].x, xvv[j].y, xvv[j].z, xvv[j].w};
        float ca[4] = {cv.x, cv.y, cv.z, cv.w};
        #pragma unroll
        for (int e = 0; e < 4; ++e)
            ov[e] = (xa[e] + ca[e]) * t4v[j][e];
        *(float4*)(out + (size_t)n * CHW_ + (size_t)o * HW_ + h * W_ + w) =
            make_float4(ov[0], ov[1], ov[2], ov[3]);
    }
}

extern "C" void kernel_launch(void* const* d_in, const int* in_sizes, int n_in,
                              void* d_out, int out_size, void* d_ws, size_t ws_size,
                              hipStream_t stream) {
    const float* x   = (const float*)d_in[0];
    const float* Wc  = (const float*)d_in[1];
    const float* p4w = (const float*)d_in[2];
    float* out       = (float*)d_out;
    uint4* Apack     = (uint4*)d_ws;   // 14*4*64*16 = 57344 B

    prepack_kernel<<<14, 256, 0, stream>>>(Wc, Apack);
    fused_mfma_kernel<<<N_ * H_, 256, 0, stream>>>(x, Apack, p4w, out);
}